// Round 1
// baseline (3712.853 us; speedup 1.0000x reference)
//
#include <hip/hip_runtime.h>
#include <cstdint>

#define B_   8
#define N_   8192
#define M_   2048
#define CIN  64
#define COUT 128

__device__ __forceinline__ float sq3(float dx, float dy, float dz) {
    return __fadd_rn(__fadd_rn(__fmul_rn(dx, dx), __fmul_rn(dy, dy)), __fmul_rn(dz, dz));
}

// ---------------- FPS: one block per batch, exact-IEEE to match JAX trajectory ----------------
__global__ __launch_bounds__(1024) void fps_kernel(const float* __restrict__ p1, float* __restrict__ p2) {
    int b = blockIdx.x;
    const float* pb = p1 + (size_t)b * N_ * 3;
    float* p2b = p2 + (size_t)b * M_ * 3;
    int t = threadIdx.x;
    int lane = t & 63, wave = t >> 6;
    __shared__ float wv[32];
    __shared__ int   wi[32];

    float px[8], py[8], pz[8], dist[8];
#pragma unroll
    for (int j = 0; j < 8; ++j) {
        int idx = t + j * 1024;
        px[j] = pb[3 * idx]; py[j] = pb[3 * idx + 1]; pz[j] = pb[3 * idx + 2];
        dist[j] = 1e10f;
    }
    float sx = pb[0], sy = pb[1], sz = pb[2];
    if (t == 0) { p2b[0] = sx; p2b[1] = sy; p2b[2] = sz; }

    for (int i = 1; i < M_; ++i) {
        float bestv = -1.0f; int besti = 0;
#pragma unroll
        for (int j = 0; j < 8; ++j) {
            float d = sq3(__fsub_rn(px[j], sx), __fsub_rn(py[j], sy), __fsub_rn(pz[j], sz));
            float nd = fminf(dist[j], d);
            dist[j] = nd;
            if (nd > bestv) { bestv = nd; besti = t + j * 1024; }   // strict > : first index wins
        }
        // wave argmax, tie -> smaller index (matches jnp.argmax first-occurrence)
#pragma unroll
        for (int off = 32; off >= 1; off >>= 1) {
            float v2 = __shfl_xor(bestv, off);
            int   i2 = __shfl_xor(besti, off);
            if (v2 > bestv || (v2 == bestv && i2 < besti)) { bestv = v2; besti = i2; }
        }
        int buf = (i & 1) << 4;                      // double-buffer -> single barrier/iter
        if (lane == 0) { wv[buf + wave] = bestv; wi[buf + wave] = besti; }
        __syncthreads();
        float rv = wv[buf + (lane & 15)];
        int   ri = wi[buf + (lane & 15)];
#pragma unroll
        for (int off = 8; off >= 1; off >>= 1) {
            float v2 = __shfl_xor(rv, off);
            int   i2 = __shfl_xor(ri, off);
            if (v2 > rv || (v2 == rv && i2 < ri)) { rv = v2; ri = i2; }
        }
        int w = __builtin_amdgcn_readfirstlane(ri);
        sx = pb[3 * w]; sy = pb[3 * w + 1]; sz = pb[3 * w + 2];
        if (t == 0) { p2b[3 * i] = sx; p2b[3 * i + 1] = sy; p2b[3 * i + 2] = sz; }
    }
}

// ---------------- GEMM: h[r][c] = dot(x[r,:64], W[c,:64]) ----------------
__global__ __launch_bounds__(256) void gemm_kernel(const float* __restrict__ x, const float* __restrict__ W,
                                                   float* __restrict__ h) {
    __shared__ float xs[64][65];
    __shared__ float ws[128][65];
    int t = threadIdx.x;
    size_t rowBase = (size_t)blockIdx.x * 64;
    for (int idx = t; idx < COUT * CIN; idx += 256) ws[idx >> 6][idx & 63] = W[idx];
    const float* xb = x + rowBase * CIN;
    for (int idx = t; idx < 64 * CIN; idx += 256) xs[idx >> 6][idx & 63] = xb[idx];
    __syncthreads();
    int r0 = (t & 15) * 4, c0 = (t >> 4) * 8;
    float acc[4][8];
#pragma unroll
    for (int i = 0; i < 4; ++i)
#pragma unroll
        for (int j = 0; j < 8; ++j) acc[i][j] = 0.f;
    for (int k = 0; k < CIN; ++k) {
        float xv[4], wvv[8];
#pragma unroll
        for (int i = 0; i < 4; ++i) xv[i] = xs[r0 + i][k];
#pragma unroll
        for (int j = 0; j < 8; ++j) wvv[j] = ws[c0 + j][k];
#pragma unroll
        for (int i = 0; i < 4; ++i)
#pragma unroll
            for (int j = 0; j < 8; ++j) acc[i][j] = fmaf(xv[i], wvv[j], acc[i][j]);
    }
#pragma unroll
    for (int i = 0; i < 4; ++i) {
        size_t o = (rowBase + r0 + i) * COUT + c0;
        *(float4*)&h[o]     = make_float4(acc[i][0], acc[i][1], acc[i][2], acc[i][3]);
        *(float4*)&h[o + 4] = make_float4(acc[i][4], acc[i][5], acc[i][6], acc[i][7]);
    }
}

// ---------------- BN stats (two-stage, deterministic) ----------------
__global__ __launch_bounds__(256) void bn_partial(const float* __restrict__ h, float* __restrict__ psum,
                                                  float* __restrict__ psq) {
    int t = threadIdx.x;
    int c = t & 127, half = t >> 7;
    size_t base = (size_t)blockIdx.x * 256;
    float s = 0.f, q = 0.f;
    for (int it = 0; it < 128; ++it) {
        float v = h[(base + it * 2 + half) * COUT + c];
        s += v; q = fmaf(v, v, q);
    }
    __shared__ float ls[256], lq[256];
    ls[t] = s; lq[t] = q;
    __syncthreads();
    if (t < 128) {
        psum[blockIdx.x * 128 + c] = ls[t] + ls[t + 128];
        psq[blockIdx.x * 128 + c]  = lq[t] + lq[t + 128];
    }
}

__global__ void bn_final(const float* __restrict__ psum, const float* __restrict__ psq,
                         const float* __restrict__ gamma, const float* __restrict__ beta,
                         float* __restrict__ bns) {
    int c = threadIdx.x;  // 128
    float s = 0.f, q = 0.f;
    for (int i = 0; i < 256; ++i) { s += psum[i * 128 + c]; q += psq[i * 128 + c]; }
    float mean = s / 65536.0f;
    float var  = q / 65536.0f - mean * mean;
    float sc = gamma[c] * rsqrtf(var + 1e-5f);
    bns[c] = sc;
    bns[128 + c] = beta[c] - mean * sc;
}

// ---------------- kNN(16) + gather + BN-affine + ReLU + maxpool, one wave per query ----------------
__global__ __launch_bounds__(256) void knn_kernel(const float* __restrict__ p1, const float* __restrict__ p2,
                                                  const float* __restrict__ h, const float* __restrict__ bns,
                                                  float* __restrict__ y) {
    int q = blockIdx.x * 4 + (threadIdx.x >> 6);
    int lane = threadIdx.x & 63;
    int b = q >> 11;             // /M_
    const float* pb = p1 + (size_t)b * N_ * 3;
    const float* pq = p2 + (size_t)q * 3;
    float qx = pq[0], qy = pq[1], qz = pq[2];
    float sqq = __fadd_rn(__fadd_rn(__fmul_rn(qx, qx), __fmul_rn(qy, qy)), __fmul_rn(qz, qz));

    float ld = 1e30f; int li = 0;   // lanes 0..15: distributed sorted top-16
    float tau = 1e30f;

    for (int c0 = 0; c0 < N_; c0 += 64) {
        int cand = c0 + lane;
        float ax = pb[3 * cand], ay = pb[3 * cand + 1], az = pb[3 * cand + 2];
        float s1 = __fadd_rn(__fadd_rn(__fmul_rn(ax, ax), __fmul_rn(ay, ay)), __fmul_rn(az, az));
        float dt = __fadd_rn(__fadd_rn(__fmul_rn(ax, qx), __fmul_rn(ay, qy)), __fmul_rn(az, qz));
        float d  = __fsub_rn(__fadd_rn(sqq, s1), __fmul_rn(2.0f, dt));   // == ref (s2+s1) - 2*dot
        unsigned long long mk = __ballot(d < tau);
        while (mk) {
            int l = __ffsll((unsigned long long)mk) - 1;
            mk &= mk - 1;
            float dd = __shfl(d, l);
            int   ii = c0 + l;
            int pos = __popcll(__ballot(ld <= dd) & 0xFFFFull);  // ties -> after existing (smaller idx kept)
            if (pos < 16) {
                float pd = __shfl_up(ld, 1);
                int   pi = __shfl_up(li, 1);
                if (lane < 16) {
                    if (lane > pos) { ld = pd; li = pi; }
                    if (lane == pos) { ld = dd; li = ii; }
                }
                tau = __shfl(ld, 15);
            }
        }
    }

    // gather 16 neighbor rows, affine+relu+max; each lane owns channels {2*lane, 2*lane+1}
    int c = lane << 1;
    float sc0 = bns[c], sc1 = bns[c + 1];
    float sh0 = bns[128 + c], sh1 = bns[128 + c + 1];
    float a0 = -1e30f, a1 = -1e30f;
#pragma unroll
    for (int t16 = 0; t16 < 16; ++t16) {
        int nb = __shfl(li, t16);
        const float* hp = h + (((size_t)(b * N_ + nb)) << 7) + c;
        float h0 = hp[0], h1 = hp[1];
        a0 = fmaxf(a0, fmaf(h0, sc0, sh0));
        a1 = fmaxf(a1, fmaf(h1, sc1, sh1));
    }
    float2 out = make_float2(fmaxf(a0, 0.f), fmaxf(a1, 0.f));
    *(float2*)&y[((size_t)q << 7) + c] = out;
}

extern "C" void kernel_launch(void* const* d_in, const int* in_sizes, int n_in,
                              void* d_out, int out_size, void* d_ws, size_t ws_size,
                              hipStream_t stream) {
    const float* x     = (const float*)d_in[0];
    const float* p1    = (const float*)d_in[1];
    const float* W     = (const float*)d_in[2];
    const float* gamma = (const float*)d_in[3];
    const float* beta  = (const float*)d_in[4];

    float* y  = (float*)d_out;
    float* p2 = y + (size_t)B_ * M_ * COUT;        // outputs concatenated: y then p2

    float* h    = (float*)d_ws;                    // 65536 x 128 f32 = 32 MB
    float* psum = h + (size_t)B_ * N_ * COUT;
    float* psq  = psum + 256 * 128;
    float* bns  = psq + 256 * 128;

    fps_kernel<<<B_, 1024, 0, stream>>>(p1, p2);
    gemm_kernel<<<(B_ * N_) / 64, 256, 0, stream>>>(x, W, h);
    bn_partial<<<256, 256, 0, stream>>>(h, psum, psq);
    bn_final<<<1, 128, 0, stream>>>(psum, psq, gamma, beta, bns);
    knn_kernel<<<(B_ * M_) / 4, 256, 0, stream>>>(p1, p2, h, bns, y);
}

// Round 4
// 2261.806 us; speedup vs baseline: 1.6415x; 1.6415x over previous
//
#include <hip/hip_runtime.h>
#include <cstdint>

#define B_   8
#define N_   8192
#define M_   2048
#define CIN  64
#define COUT 128

typedef unsigned long long u64;

__device__ __forceinline__ float sq3(float dx, float dy, float dz) {
    return __fadd_rn(__fadd_rn(__fmul_rn(dx, dx), __fmul_rn(dy, dy)), __fmul_rn(dz, dz));
}

// ---------------- phase1: blocks 0..7 = FPS (one/batch), blocks 8..1031 = GEMM tiles ----------------
// FPS: 256 thr x 32 pts in registers, point cloud in 96KB static LDS, f64-packed-key argmax
// (key = f64(dist) | (8191-idx) in low mantissa bits -> v_max_f64 == exact (max dist, tie->min idx)).
__global__ __launch_bounds__(256) void phase1_kernel(const float* __restrict__ p1, float* __restrict__ p2,
                                                     const float* __restrict__ x, const float* __restrict__ W,
                                                     float* __restrict__ h) {
    __shared__ __align__(16) char smem[98368];   // static: gfx950 allows up to 160KB/WG
    int t = threadIdx.x;

    if (blockIdx.x < B_) {
        // -------- FPS --------
        float2* lds_xy = (float2*)smem;                 // 8192*8B = 64KB
        float*  lds_z  = (float*)(smem + 65536);        // 8192*4B = 32KB
        double* wbest  = (double*)(smem + 98304);       // 2 bufs x 4 waves

        int b = blockIdx.x;
        const float* pb = p1 + (size_t)b * N_ * 3;
        float* p2b = p2 + (size_t)b * M_ * 3;
        int lane = t & 63, wave = t >> 6;

        for (int i = t; i < N_; i += 256) {
            lds_xy[i] = make_float2(pb[3 * i], pb[3 * i + 1]);
            lds_z[i]  = pb[3 * i + 2];
        }
        __syncthreads();

        float px[32], py[32], pz[32], dist[32];
#pragma unroll
        for (int j = 0; j < 32; ++j) {
            int idx = t + j * 256;
            float2 xy = lds_xy[idx];
            px[j] = xy.x; py[j] = xy.y; pz[j] = lds_z[idx];
            dist[j] = 1e10f;
        }

        float2 s0 = lds_xy[0];
        float sx = s0.x, sy = s0.y, sz = lds_z[0];
        if (t == 0) { p2b[0] = sx; p2b[1] = sy; p2b[2] = sz; }

        for (int i = 1; i < M_; ++i) {
            float bestv = -1.0f; int besti = 0;
#pragma unroll
            for (int j = 0; j < 32; ++j) {
                float d = sq3(__fsub_rn(px[j], sx), __fsub_rn(py[j], sy), __fsub_rn(pz[j], sz));
                float nd = fminf(dist[j], d);
                dist[j] = nd;
                if (nd > bestv) { bestv = nd; besti = t + j * 256; }  // strict >: first occurrence
            }
            // f64 key: exact value ordering, tie -> min index; v_max_f64 reduce
            double key = __longlong_as_double(__double_as_longlong((double)bestv) | (u64)(8191 - besti));
#pragma unroll
            for (int off = 32; off >= 1; off >>= 1)
                key = fmax(key, __shfl_xor(key, off));
            int buf = (i & 1) << 2;                      // double-buffer -> 1 barrier/iter
            if (lane == 0) wbest[buf + wave] = key;
            __syncthreads();
            double2 a = *(double2*)&wbest[buf];
            double2 c = *(double2*)&wbest[buf + 2];
            double km = fmax(fmax(a.x, a.y), fmax(c.x, c.y));
            int w = 8191 - (int)(__double_as_longlong(km) & 0x1fff);
            float2 sxy = lds_xy[w];
            sx = sxy.x; sy = sxy.y; sz = lds_z[w];
            if (t == 0) { p2b[3 * i] = sx; p2b[3 * i + 1] = sy; p2b[3 * i + 2] = sz; }
        }
    } else {
        // -------- GEMM: h[r][c] = dot(x[r,:64], W[c,:64]) --------
        float (*xs)[65] = (float (*)[65])smem;                 // 64x65 f32 = 16640B
        float (*ws)[65] = (float (*)[65])(smem + 16640);       // 128x65 f32 = 33280B
        size_t rowBase = (size_t)(blockIdx.x - B_) * 64;
        for (int idx = t; idx < COUT * CIN; idx += 256) ws[idx >> 6][idx & 63] = W[idx];
        const float* xb = x + rowBase * CIN;
        for (int idx = t; idx < 64 * CIN; idx += 256) xs[idx >> 6][idx & 63] = xb[idx];
        __syncthreads();
        int r0 = (t & 15) * 4, c0 = (t >> 4) * 8;
        float acc[4][8];
#pragma unroll
        for (int i = 0; i < 4; ++i)
#pragma unroll
            for (int j = 0; j < 8; ++j) acc[i][j] = 0.f;
        for (int k = 0; k < CIN; ++k) {
            float xv[4], wvv[8];
#pragma unroll
            for (int i = 0; i < 4; ++i) xv[i] = xs[r0 + i][k];
#pragma unroll
            for (int j = 0; j < 8; ++j) wvv[j] = ws[c0 + j][k];
#pragma unroll
            for (int i = 0; i < 4; ++i)
#pragma unroll
                for (int j = 0; j < 8; ++j) acc[i][j] = fmaf(xv[i], wvv[j], acc[i][j]);
        }
#pragma unroll
        for (int i = 0; i < 4; ++i) {
            size_t o = (rowBase + r0 + i) * COUT + c0;
            *(float4*)&h[o]     = make_float4(acc[i][0], acc[i][1], acc[i][2], acc[i][3]);
            *(float4*)&h[o + 4] = make_float4(acc[i][4], acc[i][5], acc[i][6], acc[i][7]);
        }
    }
}

// ---------------- BN stats (two-stage, deterministic) ----------------
__global__ __launch_bounds__(256) void bn_partial(const float* __restrict__ h, float* __restrict__ psum,
                                                  float* __restrict__ psq) {
    int t = threadIdx.x;
    int c = t & 127, half = t >> 7;
    size_t base = (size_t)blockIdx.x * 256;
    float s = 0.f, q = 0.f;
    for (int it = 0; it < 128; ++it) {
        float v = h[(base + it * 2 + half) * COUT + c];
        s += v; q = fmaf(v, v, q);
    }
    __shared__ float ls[256], lq[256];
    ls[t] = s; lq[t] = q;
    __syncthreads();
    if (t < 128) {
        psum[blockIdx.x * 128 + c] = ls[t] + ls[t + 128];
        psq[blockIdx.x * 128 + c]  = lq[t] + lq[t + 128];
    }
}

__global__ void bn_final(const float* __restrict__ psum, const float* __restrict__ psq,
                         const float* __restrict__ gamma, const float* __restrict__ beta,
                         float* __restrict__ bns) {
    int c = threadIdx.x;  // 128
    float s = 0.f, q = 0.f;
    for (int i = 0; i < 256; ++i) { s += psum[i * 128 + c]; q += psq[i * 128 + c]; }
    float mean = s / 65536.0f;
    float var  = q / 65536.0f - mean * mean;
    float sc = gamma[c] * rsqrtf(var + 1e-5f);
    bns[c] = sc;
    bns[128 + c] = beta[c] - mean * sc;
}

// ---------------- kNN(16) + gather + BN-affine + ReLU + maxpool, one wave per query ----------------
__global__ __launch_bounds__(256) void knn_kernel(const float* __restrict__ p1, const float* __restrict__ p2,
                                                  const float* __restrict__ h, const float* __restrict__ bns,
                                                  float* __restrict__ y) {
    int q = blockIdx.x * 4 + (threadIdx.x >> 6);
    int lane = threadIdx.x & 63;
    int b = q >> 11;             // /M_
    const float* pb = p1 + (size_t)b * N_ * 3;
    const float* pq = p2 + (size_t)q * 3;
    float qx = pq[0], qy = pq[1], qz = pq[2];
    float sqq = __fadd_rn(__fadd_rn(__fmul_rn(qx, qx), __fmul_rn(qy, qy)), __fmul_rn(qz, qz));

    float ld = 1e30f; int li = 0;   // lanes 0..15: distributed sorted top-16
    float tau = 1e30f;

    for (int c0 = 0; c0 < N_; c0 += 64) {
        int cand = c0 + lane;
        float ax = pb[3 * cand], ay = pb[3 * cand + 1], az = pb[3 * cand + 2];
        float s1 = __fadd_rn(__fadd_rn(__fmul_rn(ax, ax), __fmul_rn(ay, ay)), __fmul_rn(az, az));
        float dt = __fadd_rn(__fadd_rn(__fmul_rn(ax, qx), __fmul_rn(ay, qy)), __fmul_rn(az, qz));
        float d  = __fsub_rn(__fadd_rn(sqq, s1), __fmul_rn(2.0f, dt));   // == ref (s2+s1) - 2*dot
        unsigned long long mk = __ballot(d < tau);
        while (mk) {
            int l = __ffsll((unsigned long long)mk) - 1;
            mk &= mk - 1;
            float dd = __shfl(d, l);
            int   ii = c0 + l;
            int pos = __popcll(__ballot(ld <= dd) & 0xFFFFull);  // ties -> after existing (smaller idx kept)
            if (pos < 16) {
                float pd = __shfl_up(ld, 1);
                int   pi = __shfl_up(li, 1);
                if (lane < 16) {
                    if (lane > pos) { ld = pd; li = pi; }
                    if (lane == pos) { ld = dd; li = ii; }
                }
                tau = __shfl(ld, 15);
            }
        }
    }

    // gather 16 neighbor rows, affine+relu+max; each lane owns channels {2*lane, 2*lane+1}
    int c = lane << 1;
    float sc0 = bns[c], sc1 = bns[c + 1];
    float sh0 = bns[128 + c], sh1 = bns[128 + c + 1];
    float a0 = -1e30f, a1 = -1e30f;
#pragma unroll
    for (int t16 = 0; t16 < 16; ++t16) {
        int nb = __shfl(li, t16);
        const float* hp = h + (((size_t)(b * N_ + nb)) << 7) + c;
        float h0 = hp[0], h1 = hp[1];
        a0 = fmaxf(a0, fmaf(h0, sc0, sh0));
        a1 = fmaxf(a1, fmaf(h1, sc1, sh1));
    }
    float2 out = make_float2(fmaxf(a0, 0.f), fmaxf(a1, 0.f));
    *(float2*)&y[((size_t)q << 7) + c] = out;
}

extern "C" void kernel_launch(void* const* d_in, const int* in_sizes, int n_in,
                              void* d_out, int out_size, void* d_ws, size_t ws_size,
                              hipStream_t stream) {
    const float* x     = (const float*)d_in[0];
    const float* p1    = (const float*)d_in[1];
    const float* W     = (const float*)d_in[2];
    const float* gamma = (const float*)d_in[3];
    const float* beta  = (const float*)d_in[4];

    float* y  = (float*)d_out;
    float* p2 = y + (size_t)B_ * M_ * COUT;        // outputs concatenated: y then p2

    float* h    = (float*)d_ws;                    // 65536 x 128 f32 = 32 MB
    float* psum = h + (size_t)B_ * N_ * COUT;
    float* psq  = psum + 256 * 128;
    float* bns  = psq + 256 * 128;

    phase1_kernel<<<B_ + (B_ * N_) / 64, 256, 0, stream>>>(p1, p2, x, W, h);   // FPS ∥ GEMM
    bn_partial<<<256, 256, 0, stream>>>(h, psum, psq);
    bn_final<<<1, 128, 0, stream>>>(psum, psq, gamma, beta, bns);
    knn_kernel<<<(B_ * M_) / 4, 256, 0, stream>>>(p1, p2, h, bns, y);
}